// Round 1
// baseline (197.134 us; speedup 1.0000x reference)
//
#include <hip/hip_runtime.h>
#include <hip/hip_bf16.h>

typedef __attribute__((ext_vector_type(8))) short short8;
typedef __attribute__((ext_vector_type(4))) float f32x4;

#define NROWS 8192
#define DIM   1024
#define NCH   256
#define CHROW 32      // rows per chunk (NCH*CHROW == NROWS)

#define BM 128
#define BN 128
#define BK 64
#define LDT 72        // padded LDS row stride in elems (144 B, multiple of 16 B)

__device__ __forceinline__ float bf2f(unsigned short u) {
    union { unsigned int i; float f; } v; v.i = ((unsigned int)u) << 16; return v.f;
}
__device__ __forceinline__ unsigned short f2bf(float f) {
    union { float f; unsigned int i; } v; v.f = f;
    unsigned int r = v.i + 0x7fffu + ((v.i >> 16) & 1u);   // round-to-nearest-even
    return (unsigned short)(r >> 16);
}

// ---------------------------------------------------------------- cvt fp32->bf16
// Covers x (8M), Wq (1M), Wk (1M) in one launch; 4 elems/thread.
__global__ __launch_bounds__(256) void cvt_all(
    const float* __restrict__ x, const float* __restrict__ Wq,
    const float* __restrict__ Wk,
    unsigned short* __restrict__ xb, unsigned short* __restrict__ wqb,
    unsigned short* __restrict__ wkb)
{
    size_t e = ((size_t)blockIdx.x * 256 + threadIdx.x) * 4;
    const size_t NX = (size_t)8 * 1024 * 1024;
    const size_t NW = (size_t)1024 * 1024;
    const float* src; unsigned short* dst; size_t off;
    if (e < NX)            { src = x;  dst = xb;  off = e; }
    else if (e < NX + NW)  { src = Wq; dst = wqb; off = e - NX; }
    else                   { src = Wk; dst = wkb; off = e - NX - NW; }
    float4 v = *(const float4*)(src + off);
    ushort4 o;
    o.x = f2bf(v.x); o.y = f2bf(v.y); o.z = f2bf(v.z); o.w = f2bf(v.w);
    *(ushort4*)(dst + off) = o;
}

// ---------------------------------------------------------------- GEMM (B^T)
// C[m,n] = sum_k A[m,k]*B[n,k] + bias[n], bf16 in, bf16 out (fp32 acc).
// grid: (M/BM, N/BN, 2)  z selects (Wq,bq,q) / (Wk,bk,k)
__global__ __launch_bounds__(256) void gemm_bt(
    const unsigned short* __restrict__ A,
    const unsigned short* __restrict__ Bq, const float* __restrict__ bq,
    unsigned short* __restrict__ Cq,
    const unsigned short* __restrict__ Bk, const float* __restrict__ bk,
    unsigned short* __restrict__ Ck)
{
    const int M = NROWS, N = DIM, K = DIM;
    const unsigned short* B = blockIdx.z ? Bk : Bq;
    const float* bias       = blockIdx.z ? bk : bq;
    unsigned short* C       = blockIdx.z ? Ck : Cq;
    (void)M;

    __shared__ short sA[BM * LDT];
    __shared__ short sB[BN * LDT];

    const int tid  = threadIdx.x;
    const int wave = tid >> 6, lane = tid & 63;
    const int quad = lane >> 4, l16 = lane & 15;
    const int m0 = blockIdx.x * BM, n0 = blockIdx.y * BN;
    const int wm = (wave >> 1) * 64, wn = (wave & 1) * 64;

    f32x4 acc[4][4];
    #pragma unroll
    for (int i = 0; i < 4; ++i)
        #pragma unroll
        for (int j = 0; j < 4; ++j) acc[i][j] = (f32x4)0.0f;

    for (int k0 = 0; k0 < K; k0 += BK) {
        __syncthreads();
        #pragma unroll
        for (int i = 0; i < 4; ++i) {
            int g   = i * 256 + tid;         // 1024 groups of 8 bf16 (16 B)
            int row = g >> 3;
            int kc  = (g & 7) * 8;
            uint4 va = *(const uint4*)(A + (size_t)(m0 + row) * K + k0 + kc);
            *(uint4*)&sA[row * LDT + kc] = va;
            uint4 vb = *(const uint4*)(B + (size_t)(n0 + row) * K + k0 + kc);
            *(uint4*)&sB[row * LDT + kc] = vb;
        }
        __syncthreads();
        #pragma unroll
        for (int ks = 0; ks < 2; ++ks) {
            const int kc = ks * 32 + quad * 8;
            short8 af[4], bfr[4];
            #pragma unroll
            for (int t = 0; t < 4; ++t)
                af[t] = *(const short8*)&sA[(wm + t * 16 + l16) * LDT + kc];
            #pragma unroll
            for (int t = 0; t < 4; ++t)
                bfr[t] = *(const short8*)&sB[(wn + t * 16 + l16) * LDT + kc];
            #pragma unroll
            for (int mt = 0; mt < 4; ++mt)
                #pragma unroll
                for (int nt = 0; nt < 4; ++nt)
                    acc[mt][nt] = __builtin_amdgcn_mfma_f32_16x16x32_bf16(
                        af[mt], bfr[nt], acc[mt][nt], 0, 0, 0);
        }
    }

    // epilogue: +bias, convert to bf16, store
    #pragma unroll
    for (int nt = 0; nt < 4; ++nt) {
        int n = n0 + wn + nt * 16 + l16;
        float bv = bias[n];
        #pragma unroll
        for (int mt = 0; mt < 4; ++mt) {
            #pragma unroll
            for (int r = 0; r < 4; ++r) {
                int m = m0 + wm + mt * 16 + quad * 4 + r;
                C[(size_t)m * N + n] = f2bf(acc[mt][nt][r] + bv);
            }
        }
    }
}

// ---------------------------------------------------------------- scan phase 1
// per-chunk column sums of k (bf16) -> sums[NCH][DIM] fp32
__global__ __launch_bounds__(256) void chunk_sum(
    const unsigned short* __restrict__ k, float* __restrict__ sums)
{
    const int t = threadIdx.x, ch = blockIdx.x;
    const int c4 = t * 4;
    float s0 = 0.f, s1 = 0.f, s2 = 0.f, s3 = 0.f;
    #pragma unroll 4
    for (int r = 0; r < CHROW; ++r) {
        size_t row = (size_t)ch * CHROW + r;
        ushort4 kv = *(const ushort4*)&k[row * DIM + c4];
        s0 += bf2f(kv.x); s1 += bf2f(kv.y); s2 += bf2f(kv.z); s3 += bf2f(kv.w);
    }
    f32x4 o; o[0] = s0; o[1] = s1; o[2] = s2; o[3] = s3;
    *(f32x4*)&sums[(size_t)ch * DIM + c4] = o;
}

// ---------------------------------------------------------------- scan phase 2
// exclusive scan over chunks per column: offs[ch][c] = sum_{j<ch} sums[j][c]
__global__ __launch_bounds__(256) void chunk_scan(
    const float* __restrict__ sums, float* __restrict__ offs)
{
    const int c4 = threadIdx.x * 4;
    f32x4 run = (f32x4)0.0f;
    #pragma unroll 8
    for (int ch = 0; ch < NCH; ++ch) {
        f32x4 v = *(const f32x4*)&sums[(size_t)ch * DIM + c4];
        *(f32x4*)&offs[(size_t)ch * DIM + c4] = run;
        run += v;
    }
}

// ---------------------------------------------------------------- finalize
// within-chunk exclusive scan of k (on the fly), r[i] = q[i]·S[i],
// broadcast-store out[i][:] = r[i]
__global__ __launch_bounds__(256) void finalize(
    const unsigned short* __restrict__ q, const unsigned short* __restrict__ k,
    const float* __restrict__ offs, float* __restrict__ out)
{
    __shared__ float red[4];
    const int t = threadIdx.x, ch = blockIdx.x;
    const int c4 = t * 4;
    f32x4 run = *(const f32x4*)&offs[(size_t)ch * DIM + c4];
    for (int r = 0; r < CHROW; ++r) {
        size_t row = (size_t)ch * CHROW + r;
        ushort4 qv = *(const ushort4*)&q[row * DIM + c4];
        float p = bf2f(qv.x) * run[0] + bf2f(qv.y) * run[1]
                + bf2f(qv.z) * run[2] + bf2f(qv.w) * run[3];
        #pragma unroll
        for (int s = 32; s >= 1; s >>= 1) p += __shfl_xor(p, s, 64);
        if ((t & 63) == 0) red[t >> 6] = p;
        __syncthreads();
        float rv = red[0] + red[1] + red[2] + red[3];
        f32x4 o = (f32x4)rv;
        *(f32x4*)&out[row * DIM + c4] = o;
        ushort4 kv = *(const ushort4*)&k[row * DIM + c4];
        run[0] += bf2f(kv.x); run[1] += bf2f(kv.y);
        run[2] += bf2f(kv.z); run[3] += bf2f(kv.w);
        __syncthreads();   // red[] reused next row
    }
}

// ---------------------------------------------------------------- launch
extern "C" void kernel_launch(void* const* d_in, const int* in_sizes, int n_in,
                              void* d_out, int out_size, void* d_ws, size_t ws_size,
                              hipStream_t stream)
{
    const float* x  = (const float*)d_in[0];
    const float* Wk = (const float*)d_in[1];
    const float* bk = (const float*)d_in[2];
    // d_in[3] = Wv, d_in[4] = bv : dead (reference overwrites V with ones)
    const float* Wq = (const float*)d_in[5];
    const float* bq = (const float*)d_in[6];
    float* out = (float*)d_out;

    char* ws = (char*)d_ws;
    unsigned short* xb  = (unsigned short*)(ws);                          // 16 MB
    unsigned short* wqb = (unsigned short*)(ws + (size_t)(16u << 20));    //  2 MB
    unsigned short* wkb = (unsigned short*)(ws + (size_t)(18u << 20));    //  2 MB
    unsigned short* qb  = (unsigned short*)(ws + (size_t)(20u << 20));    // 16 MB
    unsigned short* kb  = (unsigned short*)(ws + (size_t)(36u << 20));    // 16 MB
    float* sums         = (float*)(ws + (size_t)(52u << 20));             //  1 MB
    float* offs         = (float*)(ws + (size_t)(53u << 20));             //  1 MB

    // 1) convert inputs to bf16 (10M elems, 4/thread)
    cvt_all<<<10240, 256, 0, stream>>>(x, Wq, Wk, xb, wqb, wkb);
    // 2) q and k projections (bf16 MFMA, fused bias, bf16 out)
    gemm_bt<<<dim3(64, 8, 2), 256, 0, stream>>>(xb, wqb, bq, qb, wkb, bk, kb);
    // 3) 3-phase exclusive row-prefix scan of k fused with r = q·S and broadcast
    chunk_sum<<<NCH, 256, 0, stream>>>(kb, sums);
    chunk_scan<<<1, 256, 0, stream>>>(sums, offs);
    finalize<<<NCH, 256, 0, stream>>>(qb, kb, offs, out);
}

// Round 2
// 191.990 us; speedup vs baseline: 1.0268x; 1.0268x over previous
//
#include <hip/hip_runtime.h>
#include <hip/hip_bf16.h>

typedef __attribute__((ext_vector_type(8))) short short8;
typedef __attribute__((ext_vector_type(4))) float f32x4;

#define NROWS 8192
#define DIM   1024
#define NCH   256
#define CHROW 32      // rows per chunk (NCH*CHROW == NROWS)

#define BM 128
#define BN 128
#define BK 64

__device__ __forceinline__ float bf2f(unsigned short u) {
    union { unsigned int i; float f; } v; v.i = ((unsigned int)u) << 16; return v.f;
}
__device__ __forceinline__ unsigned short f2bf(float f) {
    union { float f; unsigned int i; } v; v.f = f;
    unsigned int r = v.i + 0x7fffu + ((v.i >> 16) & 1u);   // round-to-nearest-even
    return (unsigned short)(r >> 16);
}

// async global->LDS, 16 B per lane. LDS dest = wave-uniform base + lane*16.
__device__ __forceinline__ void gload_lds16(const unsigned short* g, unsigned short* l) {
    __builtin_amdgcn_global_load_lds(
        (const __attribute__((address_space(1))) void*)g,
        (__attribute__((address_space(3))) void*)l, 16, 0, 0);
}

// ---------------------------------------------------------------- cvt fp32->bf16
__global__ __launch_bounds__(256) void cvt_all(
    const float* __restrict__ x, const float* __restrict__ Wq,
    const float* __restrict__ Wk,
    unsigned short* __restrict__ xb, unsigned short* __restrict__ wqb,
    unsigned short* __restrict__ wkb)
{
    size_t e = ((size_t)blockIdx.x * 256 + threadIdx.x) * 4;
    const size_t NX = (size_t)8 * 1024 * 1024;
    const size_t NW = (size_t)1024 * 1024;
    const float* src; unsigned short* dst; size_t off;
    if (e < NX)            { src = x;  dst = xb;  off = e; }
    else if (e < NX + NW)  { src = Wq; dst = wqb; off = e - NX; }
    else                   { src = Wk; dst = wkb; off = e - NX - NW; }
    float4 v = *(const float4*)(src + off);
    ushort4 o;
    o.x = f2bf(v.x); o.y = f2bf(v.y); o.z = f2bf(v.z); o.w = f2bf(v.w);
    *(ushort4*)(dst + off) = o;
}

// ---------------------------------------------------------------- GEMM (B^T), m97 structure
// C[m,n] = sum_k A[m,k]*B[n,k] + bias[n]; bf16 in (fp32 acc), bf16 out.
// grid: (M/BM, N/BN, 2)  z selects (Wq,bq,q) / (Wk,bk,k)
__global__ __launch_bounds__(256) void gemm_bt(
    const unsigned short* __restrict__ A,
    const unsigned short* __restrict__ Bq, const float* __restrict__ bq,
    unsigned short* __restrict__ Cq,
    const unsigned short* __restrict__ Bk, const float* __restrict__ bk,
    unsigned short* __restrict__ Ck)
{
    const int N = DIM, K = DIM;
    const unsigned short* B = blockIdx.z ? Bk : Bq;
    const float* bias       = blockIdx.z ? bk : bq;
    unsigned short* C       = blockIdx.z ? Ck : Cq;

    // unpadded: global_load_lds scatters lane*16B contiguously (no pad allowed)
    __shared__ unsigned short sA[BM * BK];   // 16 KB
    __shared__ unsigned short sB[BN * BK];   // 16 KB

    const int tid  = threadIdx.x;
    const int wave = tid >> 6, lane = tid & 63;
    const int quad = lane >> 4, l16 = lane & 15;
    const int m0 = blockIdx.x * BM, n0 = blockIdx.y * BN;
    const int wm = (wave >> 1) * 64, wn = (wave & 1) * 64;

    // staging lane mapping: 8 lanes per 64-elem (128 B) row
    const int rsel = lane >> 3;          // row within 8-row group
    const int csel = (lane & 7) * 8;     // elem col within row

    f32x4 acc[4][4];
    #pragma unroll
    for (int i = 0; i < 4; ++i)
        #pragma unroll
        for (int j = 0; j < 4; ++j) acc[i][j] = (f32x4)0.0f;

    for (int k0 = 0; k0 < K; k0 += BK) {
        __syncthreads();   // LDS from previous iter fully consumed
        #pragma unroll
        for (int j = 0; j < 4; ++j) {
            const int row = wave * 32 + j * 8;   // wave covers 32 rows of the tile
            gload_lds16(A + (size_t)(m0 + row + rsel) * K + k0 + csel, &sA[row * BK]);
            gload_lds16(B + (size_t)(n0 + row + rsel) * K + k0 + csel, &sB[row * BK]);
        }
        __syncthreads();   // vmcnt(0) drain before barrier -> LDS visible
        #pragma unroll
        for (int ks = 0; ks < 2; ++ks) {
            const int kc = ks * 32 + quad * 8;
            short8 af[4], bfr[4];
            #pragma unroll
            for (int t = 0; t < 4; ++t)
                af[t] = *(const short8*)&sA[(wm + t * 16 + l16) * BK + kc];
            #pragma unroll
            for (int t = 0; t < 4; ++t)
                bfr[t] = *(const short8*)&sB[(wn + t * 16 + l16) * BK + kc];
            #pragma unroll
            for (int mt = 0; mt < 4; ++mt)
                #pragma unroll
                for (int nt = 0; nt < 4; ++nt)
                    acc[mt][nt] = __builtin_amdgcn_mfma_f32_16x16x32_bf16(
                        af[mt], bfr[nt], acc[mt][nt], 0, 0, 0);
        }
    }

    #pragma unroll
    for (int nt = 0; nt < 4; ++nt) {
        int n = n0 + wn + nt * 16 + l16;
        float bv = bias[n];
        #pragma unroll
        for (int mt = 0; mt < 4; ++mt) {
            #pragma unroll
            for (int r = 0; r < 4; ++r) {
                int m = m0 + wm + mt * 16 + quad * 4 + r;
                C[(size_t)m * N + n] = f2bf(acc[mt][nt][r] + bv);
            }
        }
    }
}

// ---------------------------------------------------------------- scan phase 1
// per-chunk column sums of k (bf16) -> sums[NCH][DIM] fp32
__global__ __launch_bounds__(256) void chunk_sum(
    const unsigned short* __restrict__ k, float* __restrict__ sums)
{
    const int t = threadIdx.x, ch = blockIdx.x;
    const int c4 = t * 4;
    float s0 = 0.f, s1 = 0.f, s2 = 0.f, s3 = 0.f;
    #pragma unroll 4
    for (int r = 0; r < CHROW; ++r) {
        size_t row = (size_t)ch * CHROW + r;
        ushort4 kv = *(const ushort4*)&k[row * DIM + c4];
        s0 += bf2f(kv.x); s1 += bf2f(kv.y); s2 += bf2f(kv.z); s3 += bf2f(kv.w);
    }
    f32x4 o; o[0] = s0; o[1] = s1; o[2] = s2; o[3] = s3;
    *(f32x4*)&sums[(size_t)ch * DIM + c4] = o;
}

// ---------------------------------------------------------------- scan phase 2
// exclusive scan over chunks, one column per thread, 4 blocks (coalesced)
__global__ __launch_bounds__(256) void chunk_scan(
    const float* __restrict__ sums, float* __restrict__ offs)
{
    const int col = blockIdx.x * 256 + threadIdx.x;
    float run = 0.f;
    #pragma unroll 8
    for (int ch = 0; ch < NCH; ++ch) {
        float v = sums[(size_t)ch * DIM + col];
        offs[(size_t)ch * DIM + col] = run;
        run += v;
    }
}

// ---------------------------------------------------------------- finalize
// within-chunk exclusive scan of k in registers, r[i] = q[i]·S[i],
// block-reduce ALL rows with 2 barriers total, broadcast-store.
__global__ __launch_bounds__(256) void finalize(
    const unsigned short* __restrict__ q, const unsigned short* __restrict__ k,
    const float* __restrict__ offs, float* __restrict__ out)
{
    __shared__ float sP[CHROW * 256];   // 32 KB: [row][thread]
    __shared__ float rowval[CHROW];
    const int t = threadIdx.x, ch = blockIdx.x;
    const int c4 = t * 4;
    f32x4 run = *(const f32x4*)&offs[(size_t)ch * DIM + c4];
    float part[CHROW];
    #pragma unroll 4
    for (int r = 0; r < CHROW; ++r) {
        size_t row = (size_t)ch * CHROW + r;
        ushort4 qv = *(const ushort4*)&q[row * DIM + c4];
        part[r] = bf2f(qv.x) * run[0] + bf2f(qv.y) * run[1]
                + bf2f(qv.z) * run[2] + bf2f(qv.w) * run[3];
        ushort4 kv = *(const ushort4*)&k[row * DIM + c4];
        run[0] += bf2f(kv.x); run[1] += bf2f(kv.y);
        run[2] += bf2f(kv.z); run[3] += bf2f(kv.w);
    }
    #pragma unroll
    for (int r = 0; r < CHROW; ++r) sP[r * 256 + t] = part[r];
    __syncthreads();
    const int wave = t >> 6, lane = t & 63;
    #pragma unroll
    for (int r8 = 0; r8 < 8; ++r8) {
        int r = wave * 8 + r8;
        float v = sP[r * 256 + lane]       + sP[r * 256 + 64 + lane]
                + sP[r * 256 + 128 + lane] + sP[r * 256 + 192 + lane];
        #pragma unroll
        for (int s = 32; s >= 1; s >>= 1) v += __shfl_xor(v, s, 64);
        if (lane == 0) rowval[r] = v;
    }
    __syncthreads();
    #pragma unroll
    for (int r = 0; r < CHROW; ++r) {
        size_t row = (size_t)ch * CHROW + r;
        f32x4 o = (f32x4)rowval[r];
        *(f32x4*)&out[row * DIM + c4] = o;
    }
}

// ---------------------------------------------------------------- launch
extern "C" void kernel_launch(void* const* d_in, const int* in_sizes, int n_in,
                              void* d_out, int out_size, void* d_ws, size_t ws_size,
                              hipStream_t stream)
{
    const float* x  = (const float*)d_in[0];
    const float* Wk = (const float*)d_in[1];
    const float* bk = (const float*)d_in[2];
    // d_in[3] = Wv, d_in[4] = bv : dead (reference overwrites V with ones)
    const float* Wq = (const float*)d_in[5];
    const float* bq = (const float*)d_in[6];
    float* out = (float*)d_out;

    char* ws = (char*)d_ws;
    unsigned short* xb  = (unsigned short*)(ws);                          // 16 MB
    unsigned short* wqb = (unsigned short*)(ws + (size_t)(16u << 20));    //  2 MB
    unsigned short* wkb = (unsigned short*)(ws + (size_t)(18u << 20));    //  2 MB
    unsigned short* qb  = (unsigned short*)(ws + (size_t)(20u << 20));    // 16 MB
    unsigned short* kb  = (unsigned short*)(ws + (size_t)(36u << 20));    // 16 MB
    float* sums         = (float*)(ws + (size_t)(52u << 20));             //  1 MB
    float* offs         = (float*)(ws + (size_t)(53u << 20));             //  1 MB

    cvt_all<<<10240, 256, 0, stream>>>(x, Wq, Wk, xb, wqb, wkb);
    gemm_bt<<<dim3(64, 8, 2), 256, 0, stream>>>(xb, wqb, bq, qb, wkb, bk, kb);
    chunk_sum<<<NCH, 256, 0, stream>>>(kb, sums);
    chunk_scan<<<4, 256, 0, stream>>>(sums, offs);
    finalize<<<NCH, 256, 0, stream>>>(qb, kb, offs, out);
}